// Round 10
// baseline (66.276 us; speedup 1.0000x reference)
//
#include <hip/hip_runtime.h>
#include <math.h>

#define Hh 16
#define Ll 2048
#define Dd 64
#define MB 32      // L / 64 blocks
#define TK 6

typedef __attribute__((ext_vector_type(8))) short s16x8;
typedef __attribute__((ext_vector_type(4))) short s16x4;
typedef __attribute__((ext_vector_type(4))) float f32x4;

static __device__ __forceinline__ unsigned short f2bf(float x) {
  unsigned int u = __float_as_uint(x);
  return (unsigned short)((u + 0x7fffu + ((u >> 16) & 1u)) >> 16);
}
static __device__ __forceinline__ float bf2f(short b) {
  return __uint_as_float(((unsigned int)(unsigned short)b) << 16);
}
// byte offset into a [64][64] bf16 tile with 128B rows, XOR-swizzled (T2)
static __device__ __forceinline__ int swz(int row, int bcol) {
  return row * 128 + (bcol ^ ((row & 7) << 4));
}

// ---------------- K1: prep, type-split (unchanged from round 9) ----------------
__global__ __launch_bounds__(256)
void k_prep(const float* __restrict__ q, const float* __restrict__ k,
            const float* __restrict__ v,
            unsigned short* __restrict__ qbf, unsigned short* __restrict__ kbf,
            unsigned short* __restrict__ vt,
            float* __restrict__ qb, float* __restrict__ kb,
            unsigned short* __restrict__ part_kv, float* __restrict__ part_ks) {
  __shared__ float tile[64][68];
  __shared__ float buf2[64][68];
  int bid = blockIdx.x;
  int hm = bid & 511;
  int h = hm >> 5, m = hm & 31;
  int t = threadIdx.x;
  int r = t >> 2, c0 = (t & 3) * 16;
  const size_t base = (size_t)hm * (64 * Dd);

  if (bid < 512) {
    {
      float4 f[4];
#pragma unroll
      for (int i = 0; i < 4; ++i) {
        f[i] = *(const float4*)(q + base + r * Dd + c0 + i * 4);
        *(float4*)&tile[r][c0 + i * 4] = f[i];
        float4 vv = *(const float4*)(v + base + r * Dd + c0 + i * 4);
        *(float4*)&buf2[r][c0 + i * 4] = vv;
      }
      const float* ff = (const float*)f;
      unsigned short* dst = qbf + base;
#pragma unroll
      for (int halfi = 0; halfi < 2; ++halfi) {
        s16x8 o;
#pragma unroll
        for (int j = 0; j < 8; ++j) o[j] = (short)f2bf(ff[halfi * 8 + j] * 0.125f);
        *(s16x8*)(dst + r * Dd + c0 + halfi * 8) = o;
      }
    }
    __syncthreads();
    if (t < 64) {
      float s = 0.f;
#pragma unroll 8
      for (int rr = 0; rr < 64; ++rr) s += tile[rr][t];
      qb[hm * 64 + t] = s * (1.0f / 64.0f);
    }
    {
      int d = t >> 2, kc = (t & 3) * 16;
      unsigned short* dst = vt + (size_t)h * Dd * Ll + (size_t)d * Ll + m * 64 + kc;
#pragma unroll
      for (int halfi = 0; halfi < 2; ++halfi) {
        s16x8 o;
#pragma unroll
        for (int j = 0; j < 8; ++j) o[j] = (short)f2bf(buf2[kc + halfi * 8 + j][d]);
        *(s16x8*)(dst + halfi * 8) = o;
      }
    }
  } else {
    float4 vr[4];
    {
      float4 f[4];
#pragma unroll
      for (int i = 0; i < 4; ++i) {
        f[i] = *(const float4*)(k + base + r * Dd + c0 + i * 4);
        *(float4*)&tile[r][c0 + i * 4] = f[i];
        vr[i] = *(const float4*)(v + base + r * Dd + c0 + i * 4);
      }
      const float* ff = (const float*)f;
      unsigned short* dst = kbf + base;
#pragma unroll
      for (int halfi = 0; halfi < 2; ++halfi) {
        s16x8 o;
#pragma unroll
        for (int j = 0; j < 8; ++j) o[j] = (short)f2bf(ff[halfi * 8 + j]);
        *(s16x8*)(dst + r * Dd + c0 + halfi * 8) = o;
      }
    }
    __syncthreads();
    if (t < 64) {
      float s = 0.f;
#pragma unroll 8
      for (int rr = 0; rr < 64; ++rr) s += tile[rr][t];
      kb[hm * 64 + t] = s * (1.0f / 64.0f);
    }
    {
      int rg = t >> 4;
      int c4 = (t & 15) * 4;
#pragma unroll
      for (int ch = 0; ch < 4; ++ch) {
        int rl = ch * 16 + rg;
        float4 kq = *(const float4*)&tile[rl][c4];
        float mx = fmaxf(fmaxf(kq.x, kq.y), fmaxf(kq.z, kq.w));
#pragma unroll
        for (int off = 8; off; off >>= 1) mx = fmaxf(mx, __shfl_xor(mx, off));
        float ex = __expf(kq.x - mx), ey = __expf(kq.y - mx);
        float ez = __expf(kq.z - mx), ew = __expf(kq.w - mx);
        float sm = ex + ey + ez + ew;
#pragma unroll
        for (int off = 8; off; off >>= 1) sm += __shfl_xor(sm, off);
        float inv = 1.0f / sm;
        *(float4*)&buf2[rl][c4] = make_float4(ex * inv, ey * inv, ez * inv, ew * inv);
      }
    }
    __syncthreads();
#pragma unroll
    for (int i = 0; i < 4; ++i) *(float4*)&tile[r][c0 + i * 4] = vr[i];
    __syncthreads();
    {
      int da0 = (t >> 4) * 4, e0 = (t & 15) * 4;
      float kvacc[4][4] = {};
      float ks4[4] = {0.f, 0.f, 0.f, 0.f};
#pragma unroll 4
      for (int rr = 0; rr < 64; ++rr) {
        float4 kf = *(const float4*)&buf2[rr][da0];
        float4 vv = *(const float4*)&tile[rr][e0];
        ks4[0] += kf.x; ks4[1] += kf.y; ks4[2] += kf.z; ks4[3] += kf.w;
        kvacc[0][0] += kf.x * vv.x; kvacc[0][1] += kf.x * vv.y; kvacc[0][2] += kf.x * vv.z; kvacc[0][3] += kf.x * vv.w;
        kvacc[1][0] += kf.y * vv.x; kvacc[1][1] += kf.y * vv.y; kvacc[1][2] += kf.y * vv.z; kvacc[1][3] += kf.y * vv.w;
        kvacc[2][0] += kf.z * vv.x; kvacc[2][1] += kf.z * vv.y; kvacc[2][2] += kf.z * vv.z; kvacc[2][3] += kf.z * vv.w;
        kvacc[3][0] += kf.w * vv.x; kvacc[3][1] += kf.w * vv.y; kvacc[3][2] += kf.w * vv.z; kvacc[3][3] += kf.w * vv.w;
      }
      unsigned short* pkv = part_kv + (size_t)hm * 4096;
#pragma unroll
      for (int i = 0; i < 4; ++i) {
        s16x4 o;
        o[0] = (short)f2bf(kvacc[i][0]); o[1] = (short)f2bf(kvacc[i][1]);
        o[2] = (short)f2bf(kvacc[i][2]); o[3] = (short)f2bf(kvacc[i][3]);
        *(s16x4*)(pkv + (da0 + i) * 64 + e0) = o;
      }
      if ((t & 15) == 0) {
#pragma unroll
        for (int i = 0; i < 4; ++i) part_ks[hm * 64 + da0 + i] = ks4[i];
      }
    }
  }
}

// ---------------- K2: topk (wave-parallel) + fold (unchanged) ----------------
__global__ __launch_bounds__(256)
void k_topk_fold(const float* __restrict__ qb, const float* __restrict__ kb,
                 int* __restrict__ lut,
                 const unsigned short* __restrict__ part_kv, const float* __restrict__ part_ks,
                 const float* __restrict__ W, float* __restrict__ ksum,
                 unsigned short* __restrict__ kvwt) {
  __shared__ float kvr[16][68];
  __shared__ float w_s[64][65];
  int blk = blockIdx.x;
  int t = threadIdx.x;
  if (blk < 128) {
    int w = t >> 6, l = t & 63;
    int hm = blk * 4 + w;
    int hh = hm >> 5;
    float val = -INFINITY;
    if (l < 32) {
      const float* qv = qb + hm * 64;
      const float* kv = kb + (hh * 32 + l) * 64;
      float s = 0.f;
#pragma unroll
      for (int d4 = 0; d4 < 16; ++d4) {
        float4 a = *(const float4*)(qv + d4 * 4);
        float4 bb = *(const float4*)(kv + d4 * 4);
        s += a.x * bb.x + a.y * bb.y + a.z * bb.z + a.w * bb.w;
      }
      val = s;
    }
    int idx = l & 31;
    for (int t6 = 0; t6 < TK; ++t6) {
      float bv = val; int bi = idx;
#pragma unroll
      for (int off = 32; off; off >>= 1) {
        float ov = __shfl_xor(bv, off);
        int oi = __shfl_xor(bi, off);
        if (ov > bv || (ov == bv && oi < bi)) { bv = ov; bi = oi; }
      }
      if (l == 0) lut[hm * TK + t6] = bi;
      if (idx == bi && l < 32) val = -INFINITY;
    }
  } else {
    int fidx = blk - 128;
    int h = fidx >> 2, qtr = fidx & 3;
    int a0 = qtr * 16;
    {
      int a = t >> 4, b4 = (t & 15) * 4;
      float4 acc = make_float4(0.f, 0.f, 0.f, 0.f);
      for (int cc = 0; cc < 32; ++cc) {
        s16x4 p = *(const s16x4*)(part_kv + (size_t)(h * 32 + cc) * 4096 + (a0 + a) * 64 + b4);
        acc.x += bf2f(p[0]); acc.y += bf2f(p[1]);
        acc.z += bf2f(p[2]); acc.w += bf2f(p[3]);
      }
      *(float4*)&kvr[a][b4] = acc;
      int r = t >> 2, cq = (t & 3) * 16;
#pragma unroll
      for (int j = 0; j < 16; ++j) w_s[r][cq + j] = W[r * 64 + cq + j];
      if (qtr == 0 && t < 64) {
        float s = 0.f;
        for (int cc = 0; cc < 32; ++cc) s += part_ks[(h * 32 + cc) * 64 + t];
        ksum[h * 64 + t] = s;
      }
    }
    __syncthreads();
    int e = t & 63, ag = t >> 6;
    float acc4[4] = {0.f, 0.f, 0.f, 0.f};
    for (int b = 0; b < 64; ++b) {
      float wv = w_s[e][b];
#pragma unroll
      for (int i = 0; i < 4; ++i) acc4[i] += kvr[ag * 4 + i][b] * wv;
    }
#pragma unroll
    for (int i = 0; i < 4; ++i)
      kvwt[h * 4096 + e * 64 + a0 + ag * 4 + i] = f2bf(acc4[i]);
  }
}

// ---------------- K3: split-K flash attention (8 waves, 2 groups x 3 kv-blocks) ----------------
__global__ __launch_bounds__(512, 4)
void k_attn(const unsigned short* __restrict__ qbf,
            const unsigned short* __restrict__ kbf,
            const unsigned short* __restrict__ vt,
            const int* __restrict__ lut,
            const unsigned short* __restrict__ kvwt,
            const float* __restrict__ ksum, const float* __restrict__ bproj,
            float* __restrict__ out) {
  __shared__ unsigned short k_s[2][4096];   // per-group K tile (single-buffered)
  __shared__ unsigned short v_s[2][4096];   // per-group V^T tile
  __shared__ unsigned short p_s[8][1024];   // per-wave P; reused as o1 (64x64 f32) in merge
  __shared__ unsigned short kvwt_s[4096];
  __shared__ float ks_s[64], b_s[64];
  __shared__ float den_s[4][16];
  __shared__ float ml_m[64], ml_l[64];

  int bid = blockIdx.x;
  int hm = (bid & 7) * 64 + (bid >> 3);     // XCD-bijective swizzle
  int h = hm >> 5, m = hm & 31;
  int t = threadIdx.x, w = t >> 6, l = t & 63;
  int grp = w >> 2, ww = w & 3, tg = t & 255;
  int g = l >> 4, c16 = l & 15;

  int nbs[3];
#pragma unroll
  for (int i = 0; i < 3; ++i) nbs[i] = lut[hm * TK + grp * 3 + i];

  const unsigned short* kh = kbf + (size_t)h * Ll * Dd;
  const unsigned short* vh = vt + (size_t)h * Dd * Ll;

  auto stage_k = [&](int nb) {
    const unsigned short* kb = kh + nb * 64 * Dd;
#pragma unroll
    for (int i = 0; i < 2; ++i) {
      int c = i * 256 + tg;
      int row = c >> 3, sub = c & 7;
      int scol = (sub ^ (row & 7)) * 8;
      __builtin_amdgcn_global_load_lds(
          (const __attribute__((address_space(1))) void*)(kb + row * Dd + scol),
          (__attribute__((address_space(3))) void*)&k_s[grp][c * 8], 16, 0, 0);
    }
  };
  auto stage_v = [&](int nb) {
    const unsigned short* vb = vh + nb * 64;
#pragma unroll
    for (int i = 0; i < 2; ++i) {
      int c = i * 256 + tg;
      int row = c >> 3, sub = c & 7;
      int scol = (sub ^ (row & 7)) * 8;
      __builtin_amdgcn_global_load_lds(
          (const __attribute__((address_space(1))) void*)(vb + (size_t)row * Ll + scol),
          (__attribute__((address_space(3))) void*)&v_s[grp][c * 8], 16, 0, 0);
    }
  };

  // prologue: K[0] in flight ASAP; register/LDS prologue under it
  stage_k(nbs[0]);

  const unsigned short* qg = qbf + ((size_t)h * Ll + m * 64) * Dd;
  s16x8 aq[2];
#pragma unroll
  for (int kc = 0; kc < 2; ++kc)
    aq[kc] = *(const s16x8*)(qg + (ww * 16 + c16) * Dd + kc * 32 + g * 8);

  {
    int row = t >> 3, col8 = t & 7;
    s16x8 val = *(const s16x8*)(kvwt + h * 4096 + row * 64 + col8 * 8);
    *(s16x8*)&kvwt_s[swz(row, col8 * 16) >> 1] = val;
  }
  if (t < 64) { ks_s[t] = ksum[h * 64 + t]; b_s[t] = bproj[t]; }

  float mrow[4] = {-INFINITY, -INFINITY, -INFINITY, -INFINITY};
  float lrow[4] = {0.f, 0.f, 0.f, 0.f};
  f32x4 o[4] = {};

#pragma unroll
  for (int i = 0; i < 3; ++i) {
    // top: K[i] (issued last iter / prologue) fully landed; all waves synced.
    asm volatile("s_waitcnt vmcnt(0)" ::: "memory");
    __builtin_amdgcn_sched_barrier(0);
    __builtin_amdgcn_s_barrier();
    __builtin_amdgcn_sched_barrier(0);
    stage_v(nbs[i]);                         // V[i] lands under QK+softmax

    f32x4 s[4];
    __builtin_amdgcn_s_setprio(1);
#pragma unroll
    for (int nt = 0; nt < 4; ++nt) {
      s16x8 b0 = *(const s16x8*)&k_s[grp][swz(nt * 16 + c16, g * 16) >> 1];
      s16x8 b1 = *(const s16x8*)&k_s[grp][swz(nt * 16 + c16, 64 + g * 16) >> 1];
      f32x4 z = {0.f, 0.f, 0.f, 0.f};
      z = __builtin_amdgcn_mfma_f32_16x16x32_bf16(aq[0], b0, z, 0, 0, 0);
      s[nt] = __builtin_amdgcn_mfma_f32_16x16x32_bf16(aq[1], b1, z, 0, 0, 0);
    }
    __builtin_amdgcn_s_setprio(0);

    // all waves done reading K tile -> safe to overwrite with K[i+1]
    __builtin_amdgcn_sched_barrier(0);
    __builtin_amdgcn_s_barrier();
    __builtin_amdgcn_sched_barrier(0);
    if (i < 2) stage_k(nbs[i + 1]);          // K[i+1] lands under softmax+PV

    // online softmax (in-register, per row)
#pragma unroll
    for (int r = 0; r < 4; ++r) {
      float mx = fmaxf(fmaxf(s[0][r], s[1][r]), fmaxf(s[2][r], s[3][r]));
#pragma unroll
      for (int off = 8; off; off >>= 1) mx = fmaxf(mx, __shfl_xor(mx, off));
      float nm = fmaxf(mrow[r], mx);
      float rs = __expf(mrow[r] - nm);
      float sum = 0.f;
      int qrow = g * 4 + r;
#pragma unroll
      for (int nt = 0; nt < 4; ++nt) {
        float pv = __expf(s[nt][r] - nm);
        sum += pv;
        p_s[w][swz(qrow, (nt * 16 + c16) * 2) >> 1] = f2bf(pv);
      }
#pragma unroll
      for (int off = 8; off; off >>= 1) sum += __shfl_xor(sum, off);
      lrow[r] = lrow[r] * rs + sum;
      mrow[r] = nm;
      o[0][r] *= rs; o[1][r] *= rs; o[2][r] *= rs; o[3][r] *= rs;
    }

    // V[i] ready (K[i+1] may remain in flight)
    if (i < 2) { asm volatile("s_waitcnt vmcnt(2)" ::: "memory"); }
    else       { asm volatile("s_waitcnt vmcnt(0)" ::: "memory"); }
    __builtin_amdgcn_sched_barrier(0);
    __builtin_amdgcn_s_barrier();
    __builtin_amdgcn_sched_barrier(0);

    // wave-private p_s RAW drain
    asm volatile("s_waitcnt lgkmcnt(0)" ::: "memory");
    __builtin_amdgcn_sched_barrier(0);

    s16x8 ap0 = *(const s16x8*)&p_s[w][swz(c16, g * 16) >> 1];
    s16x8 ap1 = *(const s16x8*)&p_s[w][swz(c16, 64 + g * 16) >> 1];
    __builtin_amdgcn_s_setprio(1);
#pragma unroll
    for (int nt = 0; nt < 4; ++nt) {
      s16x8 b0 = *(const s16x8*)&v_s[grp][swz(nt * 16 + c16, g * 16) >> 1];
      s16x8 b1 = *(const s16x8*)&v_s[grp][swz(nt * 16 + c16, 64 + g * 16) >> 1];
      o[nt] = __builtin_amdgcn_mfma_f32_16x16x32_bf16(ap0, b0, o[nt], 0, 0, 0);
      o[nt] = __builtin_amdgcn_mfma_f32_16x16x32_bf16(ap1, b1, o[nt], 0, 0, 0);
    }
    __builtin_amdgcn_s_setprio(0);
  }

  // ---- merge phase ----
  __builtin_amdgcn_sched_barrier(0);
  __builtin_amdgcn_s_barrier();            // all PV reads of p_s/v_s done
  __builtin_amdgcn_sched_barrier(0);

  float* o1 = (float*)&p_s[0][0];          // 64x64 f32 (reuses p_s, 16 KB)

  f32x4 ol[4];
  if (grp == 1) {
    // dump partials for group-0 merge
#pragma unroll
    for (int r = 0; r < 4; ++r) {
      int grow = ww * 16 + g * 4 + r;
#pragma unroll
      for (int nt = 0; nt < 4; ++nt) o1[grow * 64 + nt * 16 + c16] = o[nt][r];
      if (c16 == 0) { ml_m[grow] = mrow[r]; ml_l[grow] = lrow[r]; }
    }
    asm volatile("s_waitcnt lgkmcnt(0)" ::: "memory");
  } else {
    // linear-attention part (in-register qf softmax), overlapped with grp1 dump
    float qf0[8], qf1[8];
    float mx = -INFINITY;
#pragma unroll
    for (int j = 0; j < 8; ++j) {
      qf0[j] = bf2f(aq[0][j]) * 8.f;
      qf1[j] = bf2f(aq[1][j]) * 8.f;
      mx = fmaxf(mx, fmaxf(qf0[j], qf1[j]));
    }
    mx = fmaxf(mx, __shfl_xor(mx, 16));
    mx = fmaxf(mx, __shfl_xor(mx, 32));
    float sm = 0.f;
#pragma unroll
    for (int j = 0; j < 8; ++j) {
      qf0[j] = __expf(qf0[j] - mx);
      qf1[j] = __expf(qf1[j] - mx);
      sm += qf0[j] + qf1[j];
    }
    sm += __shfl_xor(sm, 16);
    sm += __shfl_xor(sm, 32);
    float qinv = 1.0f / sm;
    float dp = 0.f;
#pragma unroll
    for (int j = 0; j < 8; ++j) {
      qf0[j] *= qinv; qf1[j] *= qinv;
      dp += qf0[j] * ks_s[g * 8 + j] + qf1[j] * ks_s[32 + g * 8 + j];
    }
    dp += __shfl_xor(dp, 16);
    dp += __shfl_xor(dp, 32);
    if (g == 0) den_s[ww][c16] = dp + 1e-5f;
    s16x8 pa0, pa1;
#pragma unroll
    for (int j = 0; j < 8; ++j) {
      pa0[j] = (short)f2bf(qf0[j]);
      pa1[j] = (short)f2bf(qf1[j]);
    }
    asm volatile("s_waitcnt lgkmcnt(0)" ::: "memory");
    __builtin_amdgcn_sched_barrier(0);
#pragma unroll
    for (int nt = 0; nt < 4; ++nt) {
      s16x8 b0 = *(const s16x8*)&kvwt_s[swz(nt * 16 + c16, g * 16) >> 1];
      s16x8 b1 = *(const s16x8*)&kvwt_s[swz(nt * 16 + c16, 64 + g * 16) >> 1];
      f32x4 z = {0.f, 0.f, 0.f, 0.f};
      z = __builtin_amdgcn_mfma_f32_16x16x32_bf16(pa0, b0, z, 0, 0, 0);
      ol[nt] = __builtin_amdgcn_mfma_f32_16x16x32_bf16(pa1, b1, z, 0, 0, 0);
    }
  }

  __builtin_amdgcn_sched_barrier(0);
  __builtin_amdgcn_s_barrier();            // grp1 partials visible
  __builtin_amdgcn_sched_barrier(0);

  if (grp == 0) {
    float* ob = out + ((size_t)h * Ll + m * 64 + ww * 16) * Dd;
#pragma unroll
    for (int r = 0; r < 4; ++r) {
      int qrow = g * 4 + r;
      int grow = ww * 16 + qrow;
      float m1 = ml_m[grow], l1 = ml_l[grow];
      float mc = fmaxf(mrow[r], m1);
      float f0 = __expf(mrow[r] - mc), f1 = __expf(m1 - mc);
      float inv_l = 1.0f / (lrow[r] * f0 + l1 * f1);
      float invd = 1.0f / den_s[ww][qrow];
#pragma unroll
      for (int nt = 0; nt < 4; ++nt) {
        float o_c = o[nt][r] * f0 + o1[grow * 64 + nt * 16 + c16] * f1;
        ob[qrow * Dd + nt * 16 + c16] =
            o_c * inv_l + ol[nt][r] * invd + b_s[nt * 16 + c16];
      }
    }
  }
}

extern "C" void kernel_launch(void* const* d_in, const int* in_sizes, int n_in,
                              void* d_out, int out_size, void* d_ws, size_t ws_size,
                              hipStream_t stream) {
  const float* q = (const float*)d_in[0];
  const float* k = (const float*)d_in[1];
  const float* v = (const float*)d_in[2];
  const float* W = (const float*)d_in[3];
  const float* b = (const float*)d_in[4];
  float* out = (float*)d_out;

  char* wsb = (char*)d_ws;
  unsigned short* qbf = (unsigned short*)(wsb);              // 4 MB
  unsigned short* kbf = (unsigned short*)(wsb + 4194304);    // 4 MB
  unsigned short* vt  = (unsigned short*)(wsb + 8388608);    // 4 MB
  float* qb      = (float*)(wsb + 12582912);                 // 128 KB
  float* kb      = (float*)(wsb + 12713984);                 // 128 KB
  int*   lut     = (int*)(wsb + 12845056);                   // 12 KB
  unsigned short* part_kv = (unsigned short*)(wsb + 12857344); // 4 MB
  float* part_ks = (float*)(wsb + 17051648);                 // 128 KB
  float* ksum    = (float*)(wsb + 17182720);                 // 4 KB
  unsigned short* kvwt = (unsigned short*)(wsb + 17186816);  // 128 KB

  k_prep<<<1024, 256, 0, stream>>>(q, k, v, qbf, kbf, vt, qb, kb,
                                   part_kv, part_ks);
  k_topk_fold<<<192, 256, 0, stream>>>(qb, kb, lut, part_kv, part_ks, W, ksum, kvwt);
  k_attn<<<512, 512, 0, stream>>>(qbf, kbf, vt, lut, kvwt, ksum, b, out);
}

// Round 11
// 42.690 us; speedup vs baseline: 1.5525x; 1.5525x over previous
//
#include <hip/hip_runtime.h>
#include <math.h>

#define Hh 16
#define Ll 2048
#define Dd 64
#define MB 32      // L / 64 blocks
#define TK 6

typedef __attribute__((ext_vector_type(8))) short s16x8;
typedef __attribute__((ext_vector_type(4))) short s16x4;
typedef __attribute__((ext_vector_type(4))) float f32x4;

static __device__ __forceinline__ unsigned short f2bf(float x) {
  unsigned int u = __float_as_uint(x);
  return (unsigned short)((u + 0x7fffu + ((u >> 16) & 1u)) >> 16);
}
static __device__ __forceinline__ float bf2f(short b) {
  return __uint_as_float(((unsigned int)(unsigned short)b) << 16);
}
// byte offset into a [64][64] bf16 tile with 128B rows, XOR-swizzled (T2)
static __device__ __forceinline__ int swz(int row, int bcol) {
  return row * 128 + (bcol ^ ((row & 7) << 4));
}

// ---------------- K1: prep, type-split (unchanged from round 9) ----------------
__global__ __launch_bounds__(256)
void k_prep(const float* __restrict__ q, const float* __restrict__ k,
            const float* __restrict__ v,
            unsigned short* __restrict__ qbf, unsigned short* __restrict__ kbf,
            unsigned short* __restrict__ vt,
            float* __restrict__ qb, float* __restrict__ kb,
            unsigned short* __restrict__ part_kv, float* __restrict__ part_ks) {
  __shared__ float tile[64][68];
  __shared__ float buf2[64][68];
  int bid = blockIdx.x;
  int hm = bid & 511;
  int h = hm >> 5, m = hm & 31;
  int t = threadIdx.x;
  int r = t >> 2, c0 = (t & 3) * 16;
  const size_t base = (size_t)hm * (64 * Dd);

  if (bid < 512) {
    {
      float4 f[4];
#pragma unroll
      for (int i = 0; i < 4; ++i) {
        f[i] = *(const float4*)(q + base + r * Dd + c0 + i * 4);
        *(float4*)&tile[r][c0 + i * 4] = f[i];
        float4 vv = *(const float4*)(v + base + r * Dd + c0 + i * 4);
        *(float4*)&buf2[r][c0 + i * 4] = vv;
      }
      const float* ff = (const float*)f;
      unsigned short* dst = qbf + base;
#pragma unroll
      for (int halfi = 0; halfi < 2; ++halfi) {
        s16x8 o;
#pragma unroll
        for (int j = 0; j < 8; ++j) o[j] = (short)f2bf(ff[halfi * 8 + j] * 0.125f);
        *(s16x8*)(dst + r * Dd + c0 + halfi * 8) = o;
      }
    }
    __syncthreads();
    if (t < 64) {
      float s = 0.f;
#pragma unroll 8
      for (int rr = 0; rr < 64; ++rr) s += tile[rr][t];
      qb[hm * 64 + t] = s * (1.0f / 64.0f);
    }
    {
      int d = t >> 2, kc = (t & 3) * 16;
      unsigned short* dst = vt + (size_t)h * Dd * Ll + (size_t)d * Ll + m * 64 + kc;
#pragma unroll
      for (int halfi = 0; halfi < 2; ++halfi) {
        s16x8 o;
#pragma unroll
        for (int j = 0; j < 8; ++j) o[j] = (short)f2bf(buf2[kc + halfi * 8 + j][d]);
        *(s16x8*)(dst + halfi * 8) = o;
      }
    }
  } else {
    float4 vr[4];
    {
      float4 f[4];
#pragma unroll
      for (int i = 0; i < 4; ++i) {
        f[i] = *(const float4*)(k + base + r * Dd + c0 + i * 4);
        *(float4*)&tile[r][c0 + i * 4] = f[i];
        vr[i] = *(const float4*)(v + base + r * Dd + c0 + i * 4);
      }
      const float* ff = (const float*)f;
      unsigned short* dst = kbf + base;
#pragma unroll
      for (int halfi = 0; halfi < 2; ++halfi) {
        s16x8 o;
#pragma unroll
        for (int j = 0; j < 8; ++j) o[j] = (short)f2bf(ff[halfi * 8 + j]);
        *(s16x8*)(dst + r * Dd + c0 + halfi * 8) = o;
      }
    }
    __syncthreads();
    if (t < 64) {
      float s = 0.f;
#pragma unroll 8
      for (int rr = 0; rr < 64; ++rr) s += tile[rr][t];
      kb[hm * 64 + t] = s * (1.0f / 64.0f);
    }
    {
      int rg = t >> 4;
      int c4 = (t & 15) * 4;
#pragma unroll
      for (int ch = 0; ch < 4; ++ch) {
        int rl = ch * 16 + rg;
        float4 kq = *(const float4*)&tile[rl][c4];
        float mx = fmaxf(fmaxf(kq.x, kq.y), fmaxf(kq.z, kq.w));
#pragma unroll
        for (int off = 8; off; off >>= 1) mx = fmaxf(mx, __shfl_xor(mx, off));
        float ex = __expf(kq.x - mx), ey = __expf(kq.y - mx);
        float ez = __expf(kq.z - mx), ew = __expf(kq.w - mx);
        float sm = ex + ey + ez + ew;
#pragma unroll
        for (int off = 8; off; off >>= 1) sm += __shfl_xor(sm, off);
        float inv = 1.0f / sm;
        *(float4*)&buf2[rl][c4] = make_float4(ex * inv, ey * inv, ez * inv, ew * inv);
      }
    }
    __syncthreads();
#pragma unroll
    for (int i = 0; i < 4; ++i) *(float4*)&tile[r][c0 + i * 4] = vr[i];
    __syncthreads();
    {
      int da0 = (t >> 4) * 4, e0 = (t & 15) * 4;
      float kvacc[4][4] = {};
      float ks4[4] = {0.f, 0.f, 0.f, 0.f};
#pragma unroll 4
      for (int rr = 0; rr < 64; ++rr) {
        float4 kf = *(const float4*)&buf2[rr][da0];
        float4 vv = *(const float4*)&tile[rr][e0];
        ks4[0] += kf.x; ks4[1] += kf.y; ks4[2] += kf.z; ks4[3] += kf.w;
        kvacc[0][0] += kf.x * vv.x; kvacc[0][1] += kf.x * vv.y; kvacc[0][2] += kf.x * vv.z; kvacc[0][3] += kf.x * vv.w;
        kvacc[1][0] += kf.y * vv.x; kvacc[1][1] += kf.y * vv.y; kvacc[1][2] += kf.y * vv.z; kvacc[1][3] += kf.y * vv.w;
        kvacc[2][0] += kf.z * vv.x; kvacc[2][1] += kf.z * vv.y; kvacc[2][2] += kf.z * vv.z; kvacc[2][3] += kf.z * vv.w;
        kvacc[3][0] += kf.w * vv.x; kvacc[3][1] += kf.w * vv.y; kvacc[3][2] += kf.w * vv.z; kvacc[3][3] += kf.w * vv.w;
      }
      unsigned short* pkv = part_kv + (size_t)hm * 4096;
#pragma unroll
      for (int i = 0; i < 4; ++i) {
        s16x4 o;
        o[0] = (short)f2bf(kvacc[i][0]); o[1] = (short)f2bf(kvacc[i][1]);
        o[2] = (short)f2bf(kvacc[i][2]); o[3] = (short)f2bf(kvacc[i][3]);
        *(s16x4*)(pkv + (da0 + i) * 64 + e0) = o;
      }
      if ((t & 15) == 0) {
#pragma unroll
        for (int i = 0; i < 4; ++i) part_ks[hm * 64 + da0 + i] = ks4[i];
      }
    }
  }
}

// ---------------- K2: topk (wave-parallel) + fold (unchanged) ----------------
__global__ __launch_bounds__(256)
void k_topk_fold(const float* __restrict__ qb, const float* __restrict__ kb,
                 int* __restrict__ lut,
                 const unsigned short* __restrict__ part_kv, const float* __restrict__ part_ks,
                 const float* __restrict__ W, float* __restrict__ ksum,
                 unsigned short* __restrict__ kvwt) {
  __shared__ float kvr[16][68];
  __shared__ float w_s[64][65];
  int blk = blockIdx.x;
  int t = threadIdx.x;
  if (blk < 128) {
    int w = t >> 6, l = t & 63;
    int hm = blk * 4 + w;
    int hh = hm >> 5;
    float val = -INFINITY;
    if (l < 32) {
      const float* qv = qb + hm * 64;
      const float* kv = kb + (hh * 32 + l) * 64;
      float s = 0.f;
#pragma unroll
      for (int d4 = 0; d4 < 16; ++d4) {
        float4 a = *(const float4*)(qv + d4 * 4);
        float4 bb = *(const float4*)(kv + d4 * 4);
        s += a.x * bb.x + a.y * bb.y + a.z * bb.z + a.w * bb.w;
      }
      val = s;
    }
    int idx = l & 31;
    for (int t6 = 0; t6 < TK; ++t6) {
      float bv = val; int bi = idx;
#pragma unroll
      for (int off = 32; off; off >>= 1) {
        float ov = __shfl_xor(bv, off);
        int oi = __shfl_xor(bi, off);
        if (ov > bv || (ov == bv && oi < bi)) { bv = ov; bi = oi; }
      }
      if (l == 0) lut[hm * TK + t6] = bi;
      if (idx == bi && l < 32) val = -INFINITY;
    }
  } else {
    int fidx = blk - 128;
    int h = fidx >> 2, qtr = fidx & 3;
    int a0 = qtr * 16;
    {
      int a = t >> 4, b4 = (t & 15) * 4;
      float4 acc = make_float4(0.f, 0.f, 0.f, 0.f);
      for (int cc = 0; cc < 32; ++cc) {
        s16x4 p = *(const s16x4*)(part_kv + (size_t)(h * 32 + cc) * 4096 + (a0 + a) * 64 + b4);
        acc.x += bf2f(p[0]); acc.y += bf2f(p[1]);
        acc.z += bf2f(p[2]); acc.w += bf2f(p[3]);
      }
      *(float4*)&kvr[a][b4] = acc;
      int r = t >> 2, cq = (t & 3) * 16;
#pragma unroll
      for (int j = 0; j < 16; ++j) w_s[r][cq + j] = W[r * 64 + cq + j];
      if (qtr == 0 && t < 64) {
        float s = 0.f;
        for (int cc = 0; cc < 32; ++cc) s += part_ks[(h * 32 + cc) * 64 + t];
        ksum[h * 64 + t] = s;
      }
    }
    __syncthreads();
    int e = t & 63, ag = t >> 6;
    float acc4[4] = {0.f, 0.f, 0.f, 0.f};
    for (int b = 0; b < 64; ++b) {
      float wv = w_s[e][b];
#pragma unroll
      for (int i = 0; i < 4; ++i) acc4[i] += kvr[ag * 4 + i][b] * wv;
    }
#pragma unroll
    for (int i = 0; i < 4; ++i)
      kvwt[h * 4096 + e * 64 + a0 + ag * 4 + i] = f2bf(acc4[i]);
  }
}

// ---------------- K3: flash attention (r9 structure) + head-per-XCD mapping ----------------
__global__ __launch_bounds__(256, 2)
void k_attn(const unsigned short* __restrict__ qbf,
            const unsigned short* __restrict__ kbf,
            const unsigned short* __restrict__ vt,
            const int* __restrict__ lut,
            const unsigned short* __restrict__ kvwt,
            const float* __restrict__ ksum, const float* __restrict__ bproj,
            float* __restrict__ out) {
  __shared__ unsigned short k_s[2][4096];  // [key][d] bf16, swizzled content
  __shared__ unsigned short v_s[2][4096];  // [d][key] bf16 (V^T), swizzled content
  __shared__ unsigned short p_s[4][1024];  // per-wave [16 q][64 key] bf16, swizzled
  __shared__ unsigned short kvwt_s[4096];  // [e][a] bf16 swizzled
  __shared__ float ks_s[64], b_s[64];
  __shared__ float den_s[4][16];

  int bid = blockIdx.x;
  // head-per-XCD phased mapping: XCD x runs head x's 32 blocks, then head x+8.
  int x = bid & 7, j = bid >> 3;
  int h = x + 8 * (j >> 5);
  int m = j & 31;
  int hm = h * 32 + m;
  int t = threadIdx.x, w = t >> 6, l = t & 63;
  int g = l >> 4, c16 = l & 15;

  int nbs[TK];
#pragma unroll
  for (int i = 0; i < TK; ++i) nbs[i] = lut[hm * TK + i];

  const unsigned short* kh = kbf + (size_t)h * Ll * Dd;
  const unsigned short* vh = vt + (size_t)h * Dd * Ll;

  // linear LDS dest, pre-swizzled global source (G21)
  auto stage = [&](int buf, int nb) {
    const unsigned short* kb = kh + nb * 64 * Dd;
    const unsigned short* vb = vh + nb * 64;
#pragma unroll
    for (int i = 0; i < 2; ++i) {
      int c = i * 256 + t;
      int row = c >> 3, sub = c & 7;
      int scol = (sub ^ (row & 7)) * 8;
      __builtin_amdgcn_global_load_lds(
          (const __attribute__((address_space(1))) void*)(kb + row * Dd + scol),
          (__attribute__((address_space(3))) void*)&k_s[buf][c * 8], 16, 0, 0);
    }
#pragma unroll
    for (int i = 0; i < 2; ++i) {
      int c = i * 256 + t;
      int row = c >> 3, sub = c & 7;
      int scol = (sub ^ (row & 7)) * 8;
      __builtin_amdgcn_global_load_lds(
          (const __attribute__((address_space(1))) void*)(vb + (size_t)row * Ll + scol),
          (__attribute__((address_space(3))) void*)&v_s[buf][c * 8], 16, 0, 0);
    }
  };

  // issue first stage ASAP, overlap the rest of the prologue under it
  stage(0, nbs[0]);

  const unsigned short* qg = qbf + ((size_t)h * Ll + m * 64) * Dd;
  s16x8 aq[2];
#pragma unroll
  for (int kc = 0; kc < 2; ++kc)
    aq[kc] = *(const s16x8*)(qg + (w * 16 + c16) * Dd + kc * 32 + g * 8);

  // stage kvwt/ksum/bias for the linear epilogue
#pragma unroll
  for (int cc = 0; cc < 2; ++cc) {
    int idx = t + cc * 256;
    int row = idx >> 3, col8 = idx & 7;
    s16x8 val = *(const s16x8*)(kvwt + h * 4096 + row * 64 + col8 * 8);
    *(s16x8*)&kvwt_s[swz(row, col8 * 16) >> 1] = val;
  }
  if (t < 64) { ks_s[t] = ksum[h * 64 + t]; b_s[t] = bproj[t]; }

  float mrow[4] = {-INFINITY, -INFINITY, -INFINITY, -INFINITY};
  float lrow[4] = {0.f, 0.f, 0.f, 0.f};
  f32x4 o[4] = {};

  for (int kbi = 0; kbi < TK; ++kbi) {
    int buf = kbi & 1;
    // wait own stage loads for THIS buf (issued a full iteration ago), then sync.
    asm volatile("s_waitcnt vmcnt(0)" ::: "memory");
    __builtin_amdgcn_sched_barrier(0);
    __builtin_amdgcn_s_barrier();
    __builtin_amdgcn_sched_barrier(0);
    if (kbi + 1 < TK) stage(buf ^ 1, nbs[kbi + 1]);

    f32x4 s[4];
    __builtin_amdgcn_s_setprio(1);
#pragma unroll
    for (int nt = 0; nt < 4; ++nt) {
      s16x8 b0 = *(const s16x8*)&k_s[buf][swz(nt * 16 + c16, g * 16) >> 1];
      s16x8 b1 = *(const s16x8*)&k_s[buf][swz(nt * 16 + c16, 64 + g * 16) >> 1];
      f32x4 z = {0.f, 0.f, 0.f, 0.f};
      z = __builtin_amdgcn_mfma_f32_16x16x32_bf16(aq[0], b0, z, 0, 0, 0);
      s[nt] = __builtin_amdgcn_mfma_f32_16x16x32_bf16(aq[1], b1, z, 0, 0, 0);
    }
    __builtin_amdgcn_s_setprio(0);

#pragma unroll
    for (int r = 0; r < 4; ++r) {
      float mx = fmaxf(fmaxf(s[0][r], s[1][r]), fmaxf(s[2][r], s[3][r]));
#pragma unroll
      for (int off = 8; off; off >>= 1) mx = fmaxf(mx, __shfl_xor(mx, off));
      float nm = fmaxf(mrow[r], mx);
      float rs = __expf(mrow[r] - nm);
      float sum = 0.f;
      int qrow = g * 4 + r;
#pragma unroll
      for (int nt = 0; nt < 4; ++nt) {
        float pv = __expf(s[nt][r] - nm);
        sum += pv;
        p_s[w][swz(qrow, (nt * 16 + c16) * 2) >> 1] = f2bf(pv);
      }
#pragma unroll
      for (int off = 8; off; off >>= 1) sum += __shfl_xor(sum, off);
      lrow[r] = lrow[r] * rs + sum;
      mrow[r] = nm;
      o[0][r] *= rs; o[1][r] *= rs; o[2][r] *= rs; o[3][r] *= rs;
    }

    // wave-private p_s RAW: drain LDS writes before fragment reads
    asm volatile("s_waitcnt lgkmcnt(0)" ::: "memory");
    __builtin_amdgcn_sched_barrier(0);

    s16x8 ap0 = *(const s16x8*)&p_s[w][swz(c16, g * 16) >> 1];
    s16x8 ap1 = *(const s16x8*)&p_s[w][swz(c16, 64 + g * 16) >> 1];
    __builtin_amdgcn_s_setprio(1);
#pragma unroll
    for (int nt = 0; nt < 4; ++nt) {
      s16x8 b0 = *(const s16x8*)&v_s[buf][swz(nt * 16 + c16, g * 16) >> 1];
      s16x8 b1 = *(const s16x8*)&v_s[buf][swz(nt * 16 + c16, 64 + g * 16) >> 1];
      o[nt] = __builtin_amdgcn_mfma_f32_16x16x32_bf16(ap0, b0, o[nt], 0, 0, 0);
      o[nt] = __builtin_amdgcn_mfma_f32_16x16x32_bf16(ap1, b1, o[nt], 0, 0, 0);
    }
    __builtin_amdgcn_s_setprio(0);
  }

  // ---- fused linear-attention epilogue (in-register qf softmax) ----
  float qf0[8], qf1[8];
  float mx = -INFINITY;
#pragma unroll
  for (int j2 = 0; j2 < 8; ++j2) {
    qf0[j2] = bf2f(aq[0][j2]) * 8.f;
    qf1[j2] = bf2f(aq[1][j2]) * 8.f;
    mx = fmaxf(mx, fmaxf(qf0[j2], qf1[j2]));
  }
  mx = fmaxf(mx, __shfl_xor(mx, 16));
  mx = fmaxf(mx, __shfl_xor(mx, 32));
  float sm = 0.f;
#pragma unroll
  for (int j2 = 0; j2 < 8; ++j2) {
    qf0[j2] = __expf(qf0[j2] - mx);
    qf1[j2] = __expf(qf1[j2] - mx);
    sm += qf0[j2] + qf1[j2];
  }
  sm += __shfl_xor(sm, 16);
  sm += __shfl_xor(sm, 32);
  float qinv = 1.0f / sm;
  float dp = 0.f;
#pragma unroll
  for (int j2 = 0; j2 < 8; ++j2) {
    qf0[j2] *= qinv; qf1[j2] *= qinv;
    dp += qf0[j2] * ks_s[g * 8 + j2] + qf1[j2] * ks_s[32 + g * 8 + j2];
  }
  dp += __shfl_xor(dp, 16);
  dp += __shfl_xor(dp, 32);
  if (g == 0) den_s[w][c16] = dp + 1e-5f;
  s16x8 pa0, pa1;
#pragma unroll
  for (int j2 = 0; j2 < 8; ++j2) {
    pa0[j2] = (short)f2bf(qf0[j2]);
    pa1[j2] = (short)f2bf(qf1[j2]);
  }
  asm volatile("s_waitcnt lgkmcnt(0)" ::: "memory");
  __builtin_amdgcn_sched_barrier(0);

  f32x4 ol[4];
  __builtin_amdgcn_s_setprio(1);
#pragma unroll
  for (int nt = 0; nt < 4; ++nt) {
    s16x8 b0 = *(const s16x8*)&kvwt_s[swz(nt * 16 + c16, g * 16) >> 1];
    s16x8 b1 = *(const s16x8*)&kvwt_s[swz(nt * 16 + c16, 64 + g * 16) >> 1];
    f32x4 z = {0.f, 0.f, 0.f, 0.f};
    z = __builtin_amdgcn_mfma_f32_16x16x32_bf16(pa0, b0, z, 0, 0, 0);
    ol[nt] = __builtin_amdgcn_mfma_f32_16x16x32_bf16(pa1, b1, z, 0, 0, 0);
  }
  __builtin_amdgcn_s_setprio(0);

  float* ob = out + ((size_t)h * Ll + m * 64 + w * 16) * Dd;
#pragma unroll
  for (int r = 0; r < 4; ++r) {
    float inv_l = 1.0f / lrow[r];
    int qrow = g * 4 + r;
    float invd = 1.0f / den_s[w][qrow];
#pragma unroll
    for (int nt = 0; nt < 4; ++nt)
      ob[qrow * Dd + nt * 16 + c16] =
          o[nt][r] * inv_l + ol[nt][r] * invd + b_s[nt * 16 + c16];
  }
}

extern "C" void kernel_launch(void* const* d_in, const int* in_sizes, int n_in,
                              void* d_out, int out_size, void* d_ws, size_t ws_size,
                              hipStream_t stream) {
  const float* q = (const float*)d_in[0];
  const float* k = (const float*)d_in[1];
  const float* v = (const float*)d_in[2];
  const float* W = (const float*)d_in[3];
  const float* b = (const float*)d_in[4];
  float* out = (float*)d_out;

  char* wsb = (char*)d_ws;
  unsigned short* qbf = (unsigned short*)(wsb);              // 4 MB
  unsigned short* kbf = (unsigned short*)(wsb + 4194304);    // 4 MB
  unsigned short* vt  = (unsigned short*)(wsb + 8388608);    // 4 MB
  float* qb      = (float*)(wsb + 12582912);                 // 128 KB
  float* kb      = (float*)(wsb + 12713984);                 // 128 KB
  int*   lut     = (int*)(wsb + 12845056);                   // 12 KB
  unsigned short* part_kv = (unsigned short*)(wsb + 12857344); // 4 MB
  float* part_ks = (float*)(wsb + 17051648);                 // 128 KB
  float* ksum    = (float*)(wsb + 17182720);                 // 4 KB
  unsigned short* kvwt = (unsigned short*)(wsb + 17186816);  // 128 KB

  k_prep<<<1024, 256, 0, stream>>>(q, k, v, qbf, kbf, vt, qb, kb,
                                   part_kv, part_ks);
  k_topk_fold<<<192, 256, 0, stream>>>(qb, kb, lut, part_kv, part_ks, W, ksum, kvwt);
  k_attn<<<512, 256, 0, stream>>>(qbf, kbf, vt, lut, kvwt, ksum, b, out);
}

// Round 12
// 42.022 us; speedup vs baseline: 1.5772x; 1.0159x over previous
//
#include <hip/hip_runtime.h>
#include <math.h>

#define Hh 16
#define Ll 2048
#define Dd 64
#define MB 32      // L / 64 blocks
#define TK 6

typedef __attribute__((ext_vector_type(8))) short s16x8;
typedef __attribute__((ext_vector_type(4))) short s16x4;
typedef __attribute__((ext_vector_type(4))) float f32x4;

static __device__ __forceinline__ unsigned short f2bf(float x) {
  unsigned int u = __float_as_uint(x);
  return (unsigned short)((u + 0x7fffu + ((u >> 16) & 1u)) >> 16);
}
static __device__ __forceinline__ float bf2f(short b) {
  return __uint_as_float(((unsigned int)(unsigned short)b) << 16);
}
// byte offset into a [64][64] bf16 tile with 128B rows, XOR-swizzled (T2)
static __device__ __forceinline__ int swz(int row, int bcol) {
  return row * 128 + (bcol ^ ((row & 7) << 4));
}

// ---------------- K1: prep, type-split (unchanged from round 11) ----------------
__global__ __launch_bounds__(256)
void k_prep(const float* __restrict__ q, const float* __restrict__ k,
            const float* __restrict__ v,
            unsigned short* __restrict__ qbf, unsigned short* __restrict__ kbf,
            unsigned short* __restrict__ vt,
            float* __restrict__ qb, float* __restrict__ kb,
            unsigned short* __restrict__ part_kv, float* __restrict__ part_ks) {
  __shared__ float tile[64][68];
  __shared__ float buf2[64][68];
  int bid = blockIdx.x;
  int hm = bid & 511;
  int h = hm >> 5, m = hm & 31;
  int t = threadIdx.x;
  int r = t >> 2, c0 = (t & 3) * 16;
  const size_t base = (size_t)hm * (64 * Dd);

  if (bid < 512) {
    {
      float4 f[4];
#pragma unroll
      for (int i = 0; i < 4; ++i) {
        f[i] = *(const float4*)(q + base + r * Dd + c0 + i * 4);
        *(float4*)&tile[r][c0 + i * 4] = f[i];
        float4 vv = *(const float4*)(v + base + r * Dd + c0 + i * 4);
        *(float4*)&buf2[r][c0 + i * 4] = vv;
      }
      const float* ff = (const float*)f;
      unsigned short* dst = qbf + base;
#pragma unroll
      for (int halfi = 0; halfi < 2; ++halfi) {
        s16x8 o;
#pragma unroll
        for (int j = 0; j < 8; ++j) o[j] = (short)f2bf(ff[halfi * 8 + j] * 0.125f);
        *(s16x8*)(dst + r * Dd + c0 + halfi * 8) = o;
      }
    }
    __syncthreads();
    if (t < 64) {
      float s = 0.f;
#pragma unroll 8
      for (int rr = 0; rr < 64; ++rr) s += tile[rr][t];
      qb[hm * 64 + t] = s * (1.0f / 64.0f);
    }
    {
      int d = t >> 2, kc = (t & 3) * 16;
      unsigned short* dst = vt + (size_t)h * Dd * Ll + (size_t)d * Ll + m * 64 + kc;
#pragma unroll
      for (int halfi = 0; halfi < 2; ++halfi) {
        s16x8 o;
#pragma unroll
        for (int j = 0; j < 8; ++j) o[j] = (short)f2bf(buf2[kc + halfi * 8 + j][d]);
        *(s16x8*)(dst + halfi * 8) = o;
      }
    }
  } else {
    float4 vr[4];
    {
      float4 f[4];
#pragma unroll
      for (int i = 0; i < 4; ++i) {
        f[i] = *(const float4*)(k + base + r * Dd + c0 + i * 4);
        *(float4*)&tile[r][c0 + i * 4] = f[i];
        vr[i] = *(const float4*)(v + base + r * Dd + c0 + i * 4);
      }
      const float* ff = (const float*)f;
      unsigned short* dst = kbf + base;
#pragma unroll
      for (int halfi = 0; halfi < 2; ++halfi) {
        s16x8 o;
#pragma unroll
        for (int j = 0; j < 8; ++j) o[j] = (short)f2bf(ff[halfi * 8 + j]);
        *(s16x8*)(dst + r * Dd + c0 + halfi * 8) = o;
      }
    }
    __syncthreads();
    if (t < 64) {
      float s = 0.f;
#pragma unroll 8
      for (int rr = 0; rr < 64; ++rr) s += tile[rr][t];
      kb[hm * 64 + t] = s * (1.0f / 64.0f);
    }
    {
      int rg = t >> 4;
      int c4 = (t & 15) * 4;
#pragma unroll
      for (int ch = 0; ch < 4; ++ch) {
        int rl = ch * 16 + rg;
        float4 kq = *(const float4*)&tile[rl][c4];
        float mx = fmaxf(fmaxf(kq.x, kq.y), fmaxf(kq.z, kq.w));
#pragma unroll
        for (int off = 8; off; off >>= 1) mx = fmaxf(mx, __shfl_xor(mx, off));
        float ex = __expf(kq.x - mx), ey = __expf(kq.y - mx);
        float ez = __expf(kq.z - mx), ew = __expf(kq.w - mx);
        float sm = ex + ey + ez + ew;
#pragma unroll
        for (int off = 8; off; off >>= 1) sm += __shfl_xor(sm, off);
        float inv = 1.0f / sm;
        *(float4*)&buf2[rl][c4] = make_float4(ex * inv, ey * inv, ez * inv, ew * inv);
      }
    }
    __syncthreads();
#pragma unroll
    for (int i = 0; i < 4; ++i) *(float4*)&tile[r][c0 + i * 4] = vr[i];
    __syncthreads();
    {
      int da0 = (t >> 4) * 4, e0 = (t & 15) * 4;
      float kvacc[4][4] = {};
      float ks4[4] = {0.f, 0.f, 0.f, 0.f};
#pragma unroll 4
      for (int rr = 0; rr < 64; ++rr) {
        float4 kf = *(const float4*)&buf2[rr][da0];
        float4 vv = *(const float4*)&tile[rr][e0];
        ks4[0] += kf.x; ks4[1] += kf.y; ks4[2] += kf.z; ks4[3] += kf.w;
        kvacc[0][0] += kf.x * vv.x; kvacc[0][1] += kf.x * vv.y; kvacc[0][2] += kf.x * vv.z; kvacc[0][3] += kf.x * vv.w;
        kvacc[1][0] += kf.y * vv.x; kvacc[1][1] += kf.y * vv.y; kvacc[1][2] += kf.y * vv.z; kvacc[1][3] += kf.y * vv.w;
        kvacc[2][0] += kf.z * vv.x; kvacc[2][1] += kf.z * vv.y; kvacc[2][2] += kf.z * vv.z; kvacc[2][3] += kf.z * vv.w;
        kvacc[3][0] += kf.w * vv.x; kvacc[3][1] += kf.w * vv.y; kvacc[3][2] += kf.w * vv.z; kvacc[3][3] += kf.w * vv.w;
      }
      unsigned short* pkv = part_kv + (size_t)hm * 4096;
#pragma unroll
      for (int i = 0; i < 4; ++i) {
        s16x4 o;
        o[0] = (short)f2bf(kvacc[i][0]); o[1] = (short)f2bf(kvacc[i][1]);
        o[2] = (short)f2bf(kvacc[i][2]); o[3] = (short)f2bf(kvacc[i][3]);
        *(s16x4*)(pkv + (da0 + i) * 64 + e0) = o;
      }
      if ((t & 15) == 0) {
#pragma unroll
        for (int i = 0; i < 4; ++i) part_ks[hm * 64 + da0 + i] = ks4[i];
      }
    }
  }
}

// ---------------- K2: topk (wave-parallel) + fold (unchanged) ----------------
__global__ __launch_bounds__(256)
void k_topk_fold(const float* __restrict__ qb, const float* __restrict__ kb,
                 int* __restrict__ lut,
                 const unsigned short* __restrict__ part_kv, const float* __restrict__ part_ks,
                 const float* __restrict__ W, float* __restrict__ ksum,
                 unsigned short* __restrict__ kvwt) {
  __shared__ float kvr[16][68];
  __shared__ float w_s[64][65];
  int blk = blockIdx.x;
  int t = threadIdx.x;
  if (blk < 128) {
    int w = t >> 6, l = t & 63;
    int hm = blk * 4 + w;
    int hh = hm >> 5;
    float val = -INFINITY;
    if (l < 32) {
      const float* qv = qb + hm * 64;
      const float* kv = kb + (hh * 32 + l) * 64;
      float s = 0.f;
#pragma unroll
      for (int d4 = 0; d4 < 16; ++d4) {
        float4 a = *(const float4*)(qv + d4 * 4);
        float4 bb = *(const float4*)(kv + d4 * 4);
        s += a.x * bb.x + a.y * bb.y + a.z * bb.z + a.w * bb.w;
      }
      val = s;
    }
    int idx = l & 31;
    for (int t6 = 0; t6 < TK; ++t6) {
      float bv = val; int bi = idx;
#pragma unroll
      for (int off = 32; off; off >>= 1) {
        float ov = __shfl_xor(bv, off);
        int oi = __shfl_xor(bi, off);
        if (ov > bv || (ov == bv && oi < bi)) { bv = ov; bi = oi; }
      }
      if (l == 0) lut[hm * TK + t6] = bi;
      if (idx == bi && l < 32) val = -INFINITY;
    }
  } else {
    int fidx = blk - 128;
    int h = fidx >> 2, qtr = fidx & 3;
    int a0 = qtr * 16;
    {
      int a = t >> 4, b4 = (t & 15) * 4;
      float4 acc = make_float4(0.f, 0.f, 0.f, 0.f);
      for (int cc = 0; cc < 32; ++cc) {
        s16x4 p = *(const s16x4*)(part_kv + (size_t)(h * 32 + cc) * 4096 + (a0 + a) * 64 + b4);
        acc.x += bf2f(p[0]); acc.y += bf2f(p[1]);
        acc.z += bf2f(p[2]); acc.w += bf2f(p[3]);
      }
      *(float4*)&kvr[a][b4] = acc;
      int r = t >> 2, cq = (t & 3) * 16;
#pragma unroll
      for (int j = 0; j < 16; ++j) w_s[r][cq + j] = W[r * 64 + cq + j];
      if (qtr == 0 && t < 64) {
        float s = 0.f;
        for (int cc = 0; cc < 32; ++cc) s += part_ks[(h * 32 + cc) * 64 + t];
        ksum[h * 64 + t] = s;
      }
    }
    __syncthreads();
    int e = t & 63, ag = t >> 6;
    float acc4[4] = {0.f, 0.f, 0.f, 0.f};
    for (int b = 0; b < 64; ++b) {
      float wv = w_s[e][b];
#pragma unroll
      for (int i = 0; i < 4; ++i) acc4[i] += kvr[ag * 4 + i][b] * wv;
    }
#pragma unroll
    for (int i = 0; i < 4; ++i)
      kvwt[h * 4096 + e * 64 + a0 + ag * 4 + i] = f2bf(acc4[i]);
  }
}

// ---------------- K3: flash attention, triple-buffered counted-vmcnt pipeline ----------------
__global__ __launch_bounds__(256, 2)
void k_attn(const unsigned short* __restrict__ qbf,
            const unsigned short* __restrict__ kbf,
            const unsigned short* __restrict__ vt,
            const int* __restrict__ lut,
            const unsigned short* __restrict__ kvwt,
            const float* __restrict__ ksum, const float* __restrict__ bproj,
            float* __restrict__ out) {
  __shared__ unsigned short k_s[3][4096];  // [key][d] bf16, swizzled content
  __shared__ unsigned short v_s[3][4096];  // [d][key] bf16 (V^T), swizzled content
  __shared__ unsigned short p_s[4][1024];  // per-wave [16 q][64 key] bf16, swizzled
  __shared__ unsigned short kvwt_s[4096];  // [e][a] bf16 swizzled
  __shared__ float ks_s[64], b_s[64];
  __shared__ float den_s[4][16];

  int bid = blockIdx.x;
  // head-per-XCD phased mapping: XCD x runs head x's 32 blocks, then head x+8.
  int x = bid & 7, j = bid >> 3;
  int h = x + 8 * (j >> 5);
  int m = j & 31;
  int hm = h * 32 + m;
  int t = threadIdx.x, w = t >> 6, l = t & 63;
  int g = l >> 4, c16 = l & 15;

  // ---- prologue loads (all consumed before the staged pipeline starts) ----
  int nbs[TK];
#pragma unroll
  for (int i = 0; i < TK; ++i) nbs[i] = lut[hm * TK + i];

  const unsigned short* qg = qbf + ((size_t)h * Ll + m * 64) * Dd;
  s16x8 aq[2];
#pragma unroll
  for (int kc = 0; kc < 2; ++kc)
    aq[kc] = *(const s16x8*)(qg + (w * 16 + c16) * Dd + kc * 32 + g * 8);

#pragma unroll
  for (int cc = 0; cc < 2; ++cc) {
    int idx = t + cc * 256;
    int row = idx >> 3, col8 = idx & 7;
    s16x8 val = *(const s16x8*)(kvwt + h * 4096 + row * 64 + col8 * 8);
    *(s16x8*)&kvwt_s[swz(row, col8 * 16) >> 1] = val;
  }
  if (t < 64) { ks_s[t] = ksum[h * 64 + t]; b_s[t] = bproj[t]; }

  // drain prologue vm ops so counted waits below see only stage instructions
  asm volatile("s_waitcnt vmcnt(0)" ::: "memory");
  __builtin_amdgcn_sched_barrier(0);

  const unsigned short* kh = kbf + (size_t)h * Ll * Dd;
  const unsigned short* vh = vt + (size_t)h * Dd * Ll;

  // linear LDS dest, pre-swizzled global source (G21); 4 vm instrs per call
  auto stage = [&](int buf, int nb) {
    const unsigned short* kb = kh + nb * 64 * Dd;
    const unsigned short* vb = vh + nb * 64;
#pragma unroll
    for (int i = 0; i < 2; ++i) {
      int c = i * 256 + t;
      int row = c >> 3, sub = c & 7;
      int scol = (sub ^ (row & 7)) * 8;
      __builtin_amdgcn_global_load_lds(
          (const __attribute__((address_space(1))) void*)(kb + row * Dd + scol),
          (__attribute__((address_space(3))) void*)&k_s[buf][c * 8], 16, 0, 0);
    }
#pragma unroll
    for (int i = 0; i < 2; ++i) {
      int c = i * 256 + t;
      int row = c >> 3, sub = c & 7;
      int scol = (sub ^ (row & 7)) * 8;
      __builtin_amdgcn_global_load_lds(
          (const __attribute__((address_space(1))) void*)(vb + (size_t)row * Ll + scol),
          (__attribute__((address_space(3))) void*)&v_s[buf][c * 8], 16, 0, 0);
    }
  };

  // pipeline prologue: 2 stages in flight
  stage(0, nbs[0]);
  stage(1, nbs[1]);

  // make prologue LDS writes (kvwt_s/ks_s/b_s) visible across waves
  asm volatile("s_waitcnt lgkmcnt(0)" ::: "memory");
  __builtin_amdgcn_sched_barrier(0);
  __builtin_amdgcn_s_barrier();
  __builtin_amdgcn_sched_barrier(0);

  float mrow[4] = {-INFINITY, -INFINITY, -INFINITY, -INFINITY};
  float lrow[4] = {0.f, 0.f, 0.f, 0.f};
  f32x4 o[4] = {};

#pragma unroll
  for (int kbi = 0; kbi < TK; ++kbi) {
    int buf = kbi % 3;
    // wait for THIS buffer's stage (issued 2 iterations ago); keep next in flight
    if (kbi == TK - 1) { asm volatile("s_waitcnt vmcnt(0)" ::: "memory"); }
    else               { asm volatile("s_waitcnt vmcnt(4)" ::: "memory"); }
    __builtin_amdgcn_sched_barrier(0);
    __builtin_amdgcn_s_barrier();
    __builtin_amdgcn_sched_barrier(0);
    if (kbi + 2 < TK) stage((kbi + 2) % 3, nbs[kbi + 2]);

    f32x4 s[4];
    __builtin_amdgcn_s_setprio(1);
#pragma unroll
    for (int nt = 0; nt < 4; ++nt) {
      s16x8 b0 = *(const s16x8*)&k_s[buf][swz(nt * 16 + c16, g * 16) >> 1];
      s16x8 b1 = *(const s16x8*)&k_s[buf][swz(nt * 16 + c16, 64 + g * 16) >> 1];
      f32x4 z = {0.f, 0.f, 0.f, 0.f};
      z = __builtin_amdgcn_mfma_f32_16x16x32_bf16(aq[0], b0, z, 0, 0, 0);
      s[nt] = __builtin_amdgcn_mfma_f32_16x16x32_bf16(aq[1], b1, z, 0, 0, 0);
    }
    __builtin_amdgcn_s_setprio(0);

#pragma unroll
    for (int r = 0; r < 4; ++r) {
      float mx = fmaxf(fmaxf(s[0][r], s[1][r]), fmaxf(s[2][r], s[3][r]));
#pragma unroll
      for (int off = 8; off; off >>= 1) mx = fmaxf(mx, __shfl_xor(mx, off));
      float nm = fmaxf(mrow[r], mx);
      float rs = __expf(mrow[r] - nm);
      float sum = 0.f;
      int qrow = g * 4 + r;
#pragma unroll
      for (int nt = 0; nt < 4; ++nt) {
        float pv = __expf(s[nt][r] - nm);
        sum += pv;
        p_s[w][swz(qrow, (nt * 16 + c16) * 2) >> 1] = f2bf(pv);
      }
#pragma unroll
      for (int off = 8; off; off >>= 1) sum += __shfl_xor(sum, off);
      lrow[r] = lrow[r] * rs + sum;
      mrow[r] = nm;
      o[0][r] *= rs; o[1][r] *= rs; o[2][r] *= rs; o[3][r] *= rs;
    }

    // wave-private p_s RAW: drain LDS writes before fragment reads
    asm volatile("s_waitcnt lgkmcnt(0)" ::: "memory");
    __builtin_amdgcn_sched_barrier(0);

    s16x8 ap0 = *(const s16x8*)&p_s[w][swz(c16, g * 16) >> 1];
    s16x8 ap1 = *(const s16x8*)&p_s[w][swz(c16, 64 + g * 16) >> 1];
    __builtin_amdgcn_s_setprio(1);
#pragma unroll
    for (int nt = 0; nt < 4; ++nt) {
      s16x8 b0 = *(const s16x8*)&v_s[buf][swz(nt * 16 + c16, g * 16) >> 1];
      s16x8 b1 = *(const s16x8*)&v_s[buf][swz(nt * 16 + c16, 64 + g * 16) >> 1];
      o[nt] = __builtin_amdgcn_mfma_f32_16x16x32_bf16(ap0, b0, o[nt], 0, 0, 0);
      o[nt] = __builtin_amdgcn_mfma_f32_16x16x32_bf16(ap1, b1, o[nt], 0, 0, 0);
    }
    __builtin_amdgcn_s_setprio(0);
  }

  // ---- fused linear-attention epilogue (in-register qf softmax) ----
  float qf0[8], qf1[8];
  float mx = -INFINITY;
#pragma unroll
  for (int j2 = 0; j2 < 8; ++j2) {
    qf0[j2] = bf2f(aq[0][j2]) * 8.f;
    qf1[j2] = bf2f(aq[1][j2]) * 8.f;
    mx = fmaxf(mx, fmaxf(qf0[j2], qf1[j2]));
  }
  mx = fmaxf(mx, __shfl_xor(mx, 16));
  mx = fmaxf(mx, __shfl_xor(mx, 32));
  float sm = 0.f;
#pragma unroll
  for (int j2 = 0; j2 < 8; ++j2) {
    qf0[j2] = __expf(qf0[j2] - mx);
    qf1[j2] = __expf(qf1[j2] - mx);
    sm += qf0[j2] + qf1[j2];
  }
  sm += __shfl_xor(sm, 16);
  sm += __shfl_xor(sm, 32);
  float qinv = 1.0f / sm;
  float dp = 0.f;
#pragma unroll
  for (int j2 = 0; j2 < 8; ++j2) {
    qf0[j2] *= qinv; qf1[j2] *= qinv;
    dp += qf0[j2] * ks_s[g * 8 + j2] + qf1[j2] * ks_s[32 + g * 8 + j2];
  }
  dp += __shfl_xor(dp, 16);
  dp += __shfl_xor(dp, 32);
  if (g == 0) den_s[w][c16] = dp + 1e-5f;
  s16x8 pa0, pa1;
#pragma unroll
  for (int j2 = 0; j2 < 8; ++j2) {
    pa0[j2] = (short)f2bf(qf0[j2]);
    pa1[j2] = (short)f2bf(qf1[j2]);
  }
  asm volatile("s_waitcnt lgkmcnt(0)" ::: "memory");
  __builtin_amdgcn_sched_barrier(0);

  f32x4 ol[4];
  __builtin_amdgcn_s_setprio(1);
#pragma unroll
  for (int nt = 0; nt < 4; ++nt) {
    s16x8 b0 = *(const s16x8*)&kvwt_s[swz(nt * 16 + c16, g * 16) >> 1];
    s16x8 b1 = *(const s16x8*)&kvwt_s[swz(nt * 16 + c16, 64 + g * 16) >> 1];
    f32x4 z = {0.f, 0.f, 0.f, 0.f};
    z = __builtin_amdgcn_mfma_f32_16x16x32_bf16(pa0, b0, z, 0, 0, 0);
    ol[nt] = __builtin_amdgcn_mfma_f32_16x16x32_bf16(pa1, b1, z, 0, 0, 0);
  }
  __builtin_amdgcn_s_setprio(0);

  float* ob = out + ((size_t)h * Ll + m * 64 + w * 16) * Dd;
#pragma unroll
  for (int r = 0; r < 4; ++r) {
    float inv_l = 1.0f / lrow[r];
    int qrow = g * 4 + r;
    float invd = 1.0f / den_s[w][qrow];
#pragma unroll
    for (int nt = 0; nt < 4; ++nt)
      ob[qrow * Dd + nt * 16 + c16] =
          o[nt][r] * inv_l + ol[nt][r] * invd + b_s[nt * 16 + c16];
  }
}

extern "C" void kernel_launch(void* const* d_in, const int* in_sizes, int n_in,
                              void* d_out, int out_size, void* d_ws, size_t ws_size,
                              hipStream_t stream) {
  const float* q = (const float*)d_in[0];
  const float* k = (const float*)d_in[1];
  const float* v = (const float*)d_in[2];
  const float* W = (const float*)d_in[3];
  const float* b = (const float*)d_in[4];
  float* out = (float*)d_out;

  char* wsb = (char*)d_ws;
  unsigned short* qbf = (unsigned short*)(wsb);              // 4 MB
  unsigned short* kbf = (unsigned short*)(wsb + 4194304);    // 4 MB
  unsigned short* vt  = (unsigned short*)(wsb + 8388608);    // 4 MB
  float* qb      = (float*)(wsb + 12582912);                 // 128 KB
  float* kb      = (float*)(wsb + 12713984);                 // 128 KB
  int*   lut     = (int*)(wsb + 12845056);                   // 12 KB
  unsigned short* part_kv = (unsigned short*)(wsb + 12857344); // 4 MB
  float* part_ks = (float*)(wsb + 17051648);                 // 128 KB
  float* ksum    = (float*)(wsb + 17182720);                 // 4 KB
  unsigned short* kvwt = (unsigned short*)(wsb + 17186816);  // 128 KB

  k_prep<<<1024, 256, 0, stream>>>(q, k, v, qbf, kbf, vt, qb, kb,
                                   part_kv, part_ks);
  k_topk_fold<<<192, 256, 0, stream>>>(qb, kb, lut, part_kv, part_ks, W, ksum, kvwt);
  k_attn<<<512, 256, 0, stream>>>(qbf, kbf, vt, lut, kvwt, ksum, b, out);
}